// Round 6
// baseline (1333.794 us; speedup 1.0000x reference)
//
#include <hip/hip_runtime.h>
#include <hip/hip_bf16.h>

typedef __attribute__((ext_vector_type(8))) short bf16x8;
typedef __attribute__((ext_vector_type(4))) float f32x4;

#define SBAR() __builtin_amdgcn_sched_barrier(0)
#define WBAR() __builtin_amdgcn_s_barrier()
#define LGKM0() asm volatile("s_waitcnt lgkmcnt(0)" ::: "memory")

template<int N> __device__ __forceinline__ void vmcw() {
  if constexpr (N == 12)      asm volatile("s_waitcnt vmcnt(12)" ::: "memory");
  else if constexpr (N == 10) asm volatile("s_waitcnt vmcnt(10)" ::: "memory");
  else if constexpr (N == 8)  asm volatile("s_waitcnt vmcnt(8)" ::: "memory");
  else if constexpr (N == 4)  asm volatile("s_waitcnt vmcnt(4)" ::: "memory");
  else if constexpr (N == 2)  asm volatile("s_waitcnt vmcnt(2)" ::: "memory");
  else                        asm volatile("s_waitcnt vmcnt(0)" ::: "memory");
}

__device__ __forceinline__ ushort f2bf(float f) {
  union { float f; unsigned u; } v; v.f = f;
  unsigned r = v.u + 0x7fffu + ((v.u >> 16) & 1u);
  return (ushort)(r >> 16);
}

__device__ __forceinline__ unsigned cvtpk(float lo, float hi) {
  unsigned r;
  asm volatile("v_cvt_pk_bf16_f32 %0, %1, %2" : "=v"(r) : "v"(lo), "v"(hi));
  return r;
}

__device__ __forceinline__ void gld_lds16(const ushort* gsrc, ushort* lds) {
  __builtin_amdgcn_global_load_lds((const __attribute__((address_space(1))) void*)gsrc,
                                   (__attribute__((address_space(3))) void*)lds, 16, 0, 0);
}

__device__ __forceinline__ f32x4 MF(bf16x8 a, bf16x8 b, f32x4 c) {
  return __builtin_amdgcn_mfma_f32_16x16x32_bf16(a, b, c, 0, 0, 0);
}

__device__ __forceinline__ void xcd_map(int bid, int CT, int& r, int& c) {
  const int xcd = bid & 7, j = bid >> 3;
  r = xcd + 8 * (j / CT);
  c = j % CT;
}

__device__ __forceinline__ int expert_of(const int* g, int E, int m0) {
  int e = 0, base = 0;
  while (e < E - 1 && m0 >= base + g[e]) { base += g[e]; ++e; }
  return e;
}

// cvt 32 fp32 -> 32 bf16, write 4 kc-cells into LDS A region
__device__ __forceinline__ void store_A(ushort* L, int awr, const float4 (&av)[8]) {
#pragma unroll
  for (int cc = 0; cc < 4; ++cc) {
    uint4 w;
    w.x = cvtpk(av[2 * cc].x,     av[2 * cc].y);
    w.y = cvtpk(av[2 * cc].z,     av[2 * cc].w);
    w.z = cvtpk(av[2 * cc + 1].x, av[2 * cc + 1].y);
    w.w = cvtpk(av[2 * cc + 1].z, av[2 * cc + 1].w);
    *reinterpret_cast<uint4*>(&L[awr + cc * 2048]) = w;
  }
}

// ================= pack w1+w3: [E][D][I] fp32 -> tiled-B^T bf16 (RB=128) ======
// tile base = ((n>>7)*(D/64)+(k/64))*8192 ; within: kc*1024 + localrow*8 + (k&7)
__global__ __launch_bounds__(256) void k_pack_w13(
    const float* __restrict__ w1, const float* __restrict__ w3,
    ushort* __restrict__ w1p, ushort* __restrict__ w3p, int R, int C) {
  __shared__ ushort sm[64][66];
  const int bz = blockIdx.z;
  const int e = bz >> 1;
  const size_t mat = (size_t)R * C;
  const float* s = ((bz & 1) ? w3 : w1) + (size_t)e * mat;
  ushort* d = ((bz & 1) ? w3p : w1p) + (size_t)e * mat;
  const int c0 = blockIdx.x * 64;  // n
  const int r0 = blockIdx.y * 64;  // k
  const int t = threadIdx.x;
#pragma unroll
  for (int p = 0; p < 4; ++p) {
    const int r = p * 16 + (t >> 4);
    const float4 v = *reinterpret_cast<const float4*>(s + (size_t)(r0 + r) * C + c0 + (t & 15) * 4);
    ushort4 u; u.x = f2bf(v.x); u.y = f2bf(v.y); u.z = f2bf(v.z); u.w = f2bf(v.w);
    *reinterpret_cast<ushort4*>(&sm[r][(t & 15) * 4]) = u;
  }
  __syncthreads();
  const size_t tilebase = ((size_t)(c0 >> 7) * (R >> 6) + (r0 >> 6)) * 8192;
  const int nbase = c0 & 127;
#pragma unroll
  for (int p = 0; p < 2; ++p) {
    const int uu = p * 256 + t;
    const int kc = uu >> 6;
    const int rr = uu & 63;
    ushort u[8];
#pragma unroll
    for (int j = 0; j < 8; ++j) u[j] = sm[kc * 8 + j][rr];
    *reinterpret_cast<uint4*>(d + tilebase + (size_t)kc * 1024 + (size_t)(nbase + rr) * 8) =
        *reinterpret_cast<uint4*>(u);
  }
}

// ================= pack w2: [E][I][D] fp32 -> tiled-B^T bf16 (RB=256) ======
__global__ __launch_bounds__(256) void k_pack_w2(
    const float* __restrict__ w, ushort* __restrict__ wp, int R, int C) {
  __shared__ ushort sm[64][66];
  const int e = blockIdx.z;
  const size_t mat = (size_t)R * C;
  const float* s = w + (size_t)e * mat;
  ushort* d = wp + (size_t)e * mat;
  const int c0 = blockIdx.x * 64;  // n
  const int r0 = blockIdx.y * 64;  // k
  const int t = threadIdx.x;
#pragma unroll
  for (int p = 0; p < 4; ++p) {
    const int r = p * 16 + (t >> 4);
    const float4 v = *reinterpret_cast<const float4*>(s + (size_t)(r0 + r) * C + c0 + (t & 15) * 4);
    ushort4 u; u.x = f2bf(v.x); u.y = f2bf(v.y); u.z = f2bf(v.z); u.w = f2bf(v.w);
    *reinterpret_cast<ushort4*>(&sm[r][(t & 15) * 4]) = u;
  }
  __syncthreads();
  const size_t tilebase = ((size_t)(c0 >> 8) * (R >> 6) + (r0 >> 6)) * 16384;
  const int nbase = c0 & 255;
#pragma unroll
  for (int p = 0; p < 2; ++p) {
    const int uu = p * 256 + t;
    const int kc = uu >> 6;
    const int rr = uu & 63;
    ushort u[8];
#pragma unroll
    for (int j = 0; j < 8; ++j) u[j] = sm[kc * 8 + j][rr];
    *reinterpret_cast<uint4*>(d + tilebase + (size_t)kc * 2048 + (size_t)(nbase + rr) * 8) =
        *reinterpret_cast<uint4*>(u);
  }
}

// ================= GEMM1 tile body: 4 phases, A fp32 reg-staged, B gld_lds d=1 =====
// buf: A[0,16384) kc-major ; B1[16384,24576) ; B3[24576,32768)
template<bool PF, int CP2>
__device__ __forceinline__ void g1_tile(
    ushort* B, ushort* N,
    const float* xnext, const ushort* nB1, const ushort* nB3,
    int sto, int awr, int aoff, int b1off, int b3off,
    f32x4 (&acc1)[8][2], f32x4 (&acc3)[8][2]) {
  bf16x8 af[4], b1f[2], b3f[2];
  float4 av[8];
  // ---- P1: kh0, mi 0-3 ; issue next tile's A fp32 loads ----
  SBAR();
#pragma unroll
  for (int mi = 0; mi < 4; ++mi) af[mi] = *(const bf16x8*)&B[aoff + mi * 128];
  b1f[0] = *(const bf16x8*)&B[b1off];       b1f[1] = *(const bf16x8*)&B[b1off + 128];
  b3f[0] = *(const bf16x8*)&B[b3off];       b3f[1] = *(const bf16x8*)&B[b3off + 128];
  if (PF) {
#pragma unroll
    for (int q = 0; q < 8; ++q) av[q] = *reinterpret_cast<const float4*>(xnext + q * 4);
  }
  SBAR(); WBAR(); SBAR();
  __builtin_amdgcn_s_setprio(1);
#pragma unroll
  for (int mi = 0; mi < 4; ++mi)
#pragma unroll
    for (int ni = 0; ni < 2; ++ni) {
      acc1[mi][ni] = MF(af[mi], b1f[ni], acc1[mi][ni]);
      acc3[mi][ni] = MF(af[mi], b3f[ni], acc3[mi][ni]);
    }
  __builtin_amdgcn_s_setprio(0);
  SBAR(); WBAR();
  // ---- P2: kh0, mi 4-7 ; issue B kh0(t+1) ----
  SBAR();
#pragma unroll
  for (int mi = 0; mi < 4; ++mi) af[mi] = *(const bf16x8*)&B[aoff + (mi + 4) * 128];
  if (PF) {
    gld_lds16(nB1 + sto, N + 16384 + sto);
    gld_lds16(nB3 + sto, N + 24576 + sto);
  }
  SBAR(); WBAR(); SBAR();
  __builtin_amdgcn_s_setprio(1);
#pragma unroll
  for (int mi = 0; mi < 4; ++mi)
#pragma unroll
    for (int ni = 0; ni < 2; ++ni) {
      acc1[mi + 4][ni] = MF(af[mi], b1f[ni], acc1[mi + 4][ni]);
      acc3[mi + 4][ni] = MF(af[mi], b3f[ni], acc3[mi + 4][ni]);
    }
  __builtin_amdgcn_s_setprio(0);
  SBAR();
  vmcw<CP2>();   // retire B kh1(t)
  WBAR();
  // ---- P3: kh1, mi 0-3 ----
  SBAR();
#pragma unroll
  for (int mi = 0; mi < 4; ++mi) af[mi] = *(const bf16x8*)&B[aoff + 8192 + mi * 128];
  b1f[0] = *(const bf16x8*)&B[b1off + 4096]; b1f[1] = *(const bf16x8*)&B[b1off + 4096 + 128];
  b3f[0] = *(const bf16x8*)&B[b3off + 4096]; b3f[1] = *(const bf16x8*)&B[b3off + 4096 + 128];
  SBAR(); WBAR(); SBAR();
  __builtin_amdgcn_s_setprio(1);
#pragma unroll
  for (int mi = 0; mi < 4; ++mi)
#pragma unroll
    for (int ni = 0; ni < 2; ++ni) {
      acc1[mi][ni] = MF(af[mi], b1f[ni], acc1[mi][ni]);
      acc3[mi][ni] = MF(af[mi], b3f[ni], acc3[mi][ni]);
    }
  __builtin_amdgcn_s_setprio(0);
  SBAR(); WBAR();
  // ---- P4: kh1, mi 4-7 ; cvt+ds_write A(t+1), issue B kh1(t+1) ----
  SBAR();
#pragma unroll
  for (int mi = 0; mi < 4; ++mi) af[mi] = *(const bf16x8*)&B[aoff + 8192 + (mi + 4) * 128];
  SBAR(); WBAR(); SBAR();
  if (PF) {
    vmcw<2>();            // retire A8 (issued P1, ~3 phases slack)
    store_A(N, awr, av);  // kc-major, conflict-free per 16-lane phase
    gld_lds16(nB1 + 4096 + sto, N + 20480 + sto);
    gld_lds16(nB3 + 4096 + sto, N + 28672 + sto);
  }
  __builtin_amdgcn_s_setprio(1);
#pragma unroll
  for (int mi = 0; mi < 4; ++mi)
#pragma unroll
    for (int ni = 0; ni < 2; ++ni) {
      acc1[mi + 4][ni] = MF(af[mi], b1f[ni], acc1[mi + 4][ni]);
      acc3[mi + 4][ni] = MF(af[mi], b3f[ni], acc3[mi + 4][ni]);
    }
  __builtin_amdgcn_s_setprio(0);
  SBAR();
  if (PF) {
    LGKM0();    // ds_writes visible to all waves after the barrier
    vmcw<2>();  // retire B kh0(t+1); kh1(t+1) stays in flight
  }
  WBAR();
}

// ================= GEMM1: h = silu(x@w1)*(x@w3), 256x(128+128), BK=64 =================
__global__ __launch_bounds__(512, 2) void k_gemm1_8p(
    const float* __restrict__ x, const ushort* __restrict__ w1p,
    const ushort* __restrict__ w3p, const int* __restrict__ g,
    ushort* __restrict__ h, int T, int D, int I, int E) {
  __shared__ ushort lds[2][32768];  // 128 KiB

  const int CT = I >> 7;
  int r, c; xcd_map(blockIdx.x, CT, r, c);
  const int m0 = r << 8, n0 = c << 7;
  const int e = expert_of(g, E, m0);

  const int tid = threadIdx.x;
  const int lane = tid & 63, wave = tid >> 6;
  const int wr = wave >> 2, wc = wave & 3;
  const int l15 = lane & 15, l16 = lane >> 4;

  const int KT = D >> 6;
  const ushort* pB1 = w1p + (size_t)e * I * D + (size_t)c * (D >> 6) * 8192;
  const ushort* pB3 = w3p + (size_t)e * I * D + (size_t)c * (D >> 6) * 8192;

  const int sto = tid * 8;
  const int aoff  = l16 * 2048 + (wr * 128 + l15) * 8;
  const int b1off = 16384 + l16 * 1024 + (wc * 32 + l15) * 8;
  const int b3off = b1off + 8192;

  // A reg-staging coords: thread -> (row, k-half); 32 fp32 -> 4 kc-cells
  const int arow = tid >> 1;
  const int ahalf = tid & 1;
  const float* xptr = x + (size_t)(m0 + arow) * D + ahalf * 32;
  const int awr = ahalf * 8192 + arow * 8;

  const f32x4 zero = {0.f, 0.f, 0.f, 0.f};
  f32x4 acc1[8][2], acc3[8][2];
#pragma unroll
  for (int mi = 0; mi < 8; ++mi)
#pragma unroll
    for (int ni = 0; ni < 2; ++ni) { acc1[mi][ni] = zero; acc3[mi][ni] = zero; }

  // prologue: tile 0 — A via reg, B via gld_lds
  {
    ushort* L0 = lds[0];
    float4 pav[8];
#pragma unroll
    for (int q = 0; q < 8; ++q) pav[q] = *reinterpret_cast<const float4*>(xptr + q * 4);
    gld_lds16(pB1 + sto,        L0 + 16384 + sto);
    gld_lds16(pB3 + sto,        L0 + 24576 + sto);
    gld_lds16(pB1 + 4096 + sto, L0 + 20480 + sto);
    gld_lds16(pB3 + 4096 + sto, L0 + 28672 + sto);
    vmcw<4>();          // A8 landed
    store_A(L0, awr, pav);
    LGKM0();
    vmcw<2>();          // B kh0 landed; kh1 in flight
  }
  WBAR(); SBAR();

  int t = 0;
  for (; t < KT - 1; ++t)
    g1_tile<true, 10>(lds[t & 1], lds[(t + 1) & 1],
                      xptr + (size_t)(t + 1) * 64,
                      pB1 + (size_t)(t + 1) * 8192, pB3 + (size_t)(t + 1) * 8192,
                      sto, awr, aoff, b1off, b3off, acc1, acc3);
  g1_tile<false, 0>(lds[t & 1], lds[t & 1], xptr, pB1, pB3,
                    sto, awr, aoff, b1off, b3off, acc1, acc3);

  // epilogue: SwiGLU -> h in tiled-A layout (RB=256, K=I)
#pragma unroll
  for (int mi = 0; mi < 8; ++mi)
#pragma unroll
    for (int ni = 0; ni < 2; ++ni)
#pragma unroll
      for (int rr = 0; rr < 4; ++rr) {
        const float v1 = acc1[mi][ni][rr];
        const float v3 = acc3[mi][ni][rr];
        const float sv = v1 / (1.f + __expf(-v1));
        const int row = m0 + wr * 128 + mi * 16 + l16 * 4 + rr;
        const int col = n0 + wc * 32 + ni * 16 + l15;
        const size_t off = ((size_t)(row >> 8) * (I >> 6) + (col >> 6)) * 16384 +
                           ((col >> 3) & 7) * 2048 + (row & 255) * 8 + (col & 7);
        h[off] = f2bf(sv * v3);
      }
}

// ================= GEMM2 tile body (unchanged, prefetch distance 2) =================
template<bool PF, int C1, int C2>
__device__ __forceinline__ void g2_tile(
    ushort* B, const ushort* nA, const ushort* nB,
    int sto, int aoff, int boff, f32x4 (&acc)[8][4]) {
  bf16x8 af[4], bf[4];
  // ---- P1 ----
  SBAR();
#pragma unroll
  for (int mi = 0; mi < 4; ++mi) af[mi] = *(const bf16x8*)&B[aoff + mi * 128];
#pragma unroll
  for (int ni = 0; ni < 4; ++ni) bf[ni] = *(const bf16x8*)&B[boff + ni * 128];
  SBAR(); WBAR(); SBAR();
  __builtin_amdgcn_s_setprio(1);
#pragma unroll
  for (int mi = 0; mi < 4; ++mi)
#pragma unroll
    for (int ni = 0; ni < 4; ++ni) acc[mi][ni] = MF(af[mi], bf[ni], acc[mi][ni]);
  __builtin_amdgcn_s_setprio(0);
  SBAR(); WBAR();
  // ---- P2 ----
  SBAR();
#pragma unroll
  for (int mi = 0; mi < 4; ++mi) af[mi] = *(const bf16x8*)&B[aoff + (mi + 4) * 128];
  SBAR(); WBAR(); SBAR();
  if (PF) {
    gld_lds16(nA + sto,         B + sto);
    gld_lds16(nA + 4096 + sto,  B + 4096 + sto);
    gld_lds16(nB + sto,         B + 16384 + sto);
    gld_lds16(nB + 4096 + sto,  B + 20480 + sto);
  }
  __builtin_amdgcn_s_setprio(1);
#pragma unroll
  for (int mi = 0; mi < 4; ++mi)
#pragma unroll
    for (int ni = 0; ni < 4; ++ni) acc[mi + 4][ni] = MF(af[mi], bf[ni], acc[mi + 4][ni]);
  __builtin_amdgcn_s_setprio(0);
  SBAR();
  vmcw<C1>();
  WBAR();
  // ---- P3 ----
  SBAR();
#pragma unroll
  for (int mi = 0; mi < 4; ++mi) af[mi] = *(const bf16x8*)&B[aoff + 8192 + mi * 128];
#pragma unroll
  for (int ni = 0; ni < 4; ++ni) bf[ni] = *(const bf16x8*)&B[boff + 8192 + ni * 128];
  SBAR(); WBAR(); SBAR();
  __builtin_amdgcn_s_setprio(1);
#pragma unroll
  for (int mi = 0; mi < 4; ++mi)
#pragma unroll
    for (int ni = 0; ni < 4; ++ni) acc[mi][ni] = MF(af[mi], bf[ni], acc[mi][ni]);
  __builtin_amdgcn_s_setprio(0);
  SBAR(); WBAR();
  // ---- P4 ----
  SBAR();
#pragma unroll
  for (int mi = 0; mi < 4; ++mi) af[mi] = *(const bf16x8*)&B[aoff + 8192 + (mi + 4) * 128];
  SBAR(); WBAR(); SBAR();
  if (PF) {
    gld_lds16(nA + 8192 + sto,   B + 8192 + sto);
    gld_lds16(nA + 12288 + sto,  B + 12288 + sto);
    gld_lds16(nB + 8192 + sto,   B + 24576 + sto);
    gld_lds16(nB + 12288 + sto,  B + 28672 + sto);
  }
  __builtin_amdgcn_s_setprio(1);
#pragma unroll
  for (int mi = 0; mi < 4; ++mi)
#pragma unroll
    for (int ni = 0; ni < 4; ++ni) acc[mi + 4][ni] = MF(af[mi], bf[ni], acc[mi + 4][ni]);
  __builtin_amdgcn_s_setprio(0);
  SBAR();
  vmcw<C2>();
  WBAR();
}

// ================= GEMM2: out = h @ w2, 256x256, BK=64, fp32 out =================
__global__ __launch_bounds__(512, 2) void k_gemm2_8p(
    const ushort* __restrict__ h, const ushort* __restrict__ w2p,
    const int* __restrict__ g, float* __restrict__ out,
    int T, int D, int I, int E) {
  __shared__ ushort lds[2][32768];

  const int CT = D >> 8;
  int r, cb; xcd_map(blockIdx.x, CT, r, cb);
  const int m0 = r << 8, n0 = cb << 8;
  const int e = expert_of(g, E, m0);

  const int tid = threadIdx.x;
  const int lane = tid & 63, wave = tid >> 6;
  const int wr = wave >> 2, wc = wave & 3;
  const int l15 = lane & 15, l16 = lane >> 4;

  const int KT = I >> 6;
  const ushort* pA = h   + (size_t)r * (I >> 6) * 16384;
  const ushort* pB = w2p + (size_t)e * D * I + (size_t)cb * (I >> 6) * 16384;

  const int sto = tid * 8;
  const int aoff = l16 * 2048 + (wr * 128 + l15) * 8;
  const int boff = 16384 + l16 * 2048 + (wc * 64 + l15) * 8;

  const f32x4 zero = {0.f, 0.f, 0.f, 0.f};
  f32x4 acc[8][4];
#pragma unroll
  for (int mi = 0; mi < 8; ++mi)
#pragma unroll
    for (int ni = 0; ni < 4; ++ni) acc[mi][ni] = zero;

  {
    ushort* L0 = lds[0]; ushort* L1 = lds[1];
    gld_lds16(pA + sto,          L0 + sto);
    gld_lds16(pA + 4096 + sto,   L0 + 4096 + sto);
    gld_lds16(pB + sto,          L0 + 16384 + sto);
    gld_lds16(pB + 4096 + sto,   L0 + 20480 + sto);
    gld_lds16(pA + 8192 + sto,   L0 + 8192 + sto);
    gld_lds16(pA + 12288 + sto,  L0 + 12288 + sto);
    gld_lds16(pB + 8192 + sto,   L0 + 24576 + sto);
    gld_lds16(pB + 12288 + sto,  L0 + 28672 + sto);
    gld_lds16(pA + 16384 + sto,          L1 + sto);
    gld_lds16(pA + 16384 + 4096 + sto,   L1 + 4096 + sto);
    gld_lds16(pB + 16384 + sto,          L1 + 16384 + sto);
    gld_lds16(pB + 16384 + 4096 + sto,   L1 + 20480 + sto);
    gld_lds16(pA + 16384 + 8192 + sto,   L1 + 8192 + sto);
    gld_lds16(pA + 16384 + 12288 + sto,  L1 + 12288 + sto);
    gld_lds16(pB + 16384 + 8192 + sto,   L1 + 24576 + sto);
    gld_lds16(pB + 16384 + 12288 + sto,  L1 + 28672 + sto);
  }
  vmcw<12>(); WBAR(); SBAR();

  int t = 0;
  for (; t < KT - 2; ++t)
    g2_tile<true, 12, 12>(lds[t & 1], pA + (size_t)(t + 2) * 16384,
                          pB + (size_t)(t + 2) * 16384, sto, aoff, boff, acc);
  g2_tile<false, 8, 4>(lds[t & 1], pA, pB, sto, aoff, boff, acc);
  ++t;
  g2_tile<false, 0, 0>(lds[t & 1], pA, pB, sto, aoff, boff, acc);

#pragma unroll
  for (int mi = 0; mi < 8; ++mi)
#pragma unroll
    for (int ni = 0; ni < 4; ++ni)
#pragma unroll
      for (int rr = 0; rr < 4; ++rr) {
        const int row = m0 + wr * 128 + mi * 16 + l16 * 4 + rr;
        const int col = n0 + wc * 64 + ni * 16 + l15;
        out[(size_t)row * D + col] = acc[mi][ni][rr];
      }
}

// ================= launch =================
extern "C" void kernel_launch(void* const* d_in, const int* in_sizes, int n_in,
                              void* d_out, int out_size, void* d_ws, size_t ws_size,
                              hipStream_t stream) {
  const float* x  = (const float*)d_in[0];
  const float* w1 = (const float*)d_in[1];
  const float* w2 = (const float*)d_in[2];
  const float* w3 = (const float*)d_in[3];
  const int*   g  = (const int*)d_in[4];

  const int E = in_sizes[4];
  const int D = 4096;
  const int I = 1024;
  const int T = in_sizes[0] / D;

  const size_t szW = (size_t)E * D * I * sizeof(ushort);  // 64 MB
  const size_t szH = (size_t)T * I * sizeof(ushort);      // 64 MB
  const size_t need = 3 * szW + szH;                      // 256 MB
  if (ws_size < need) return;

  char* ws = (char*)d_ws;
  ushort* w1p = (ushort*)ws;
  ushort* w3p = (ushort*)(ws + szW);
  ushort* w2p = (ushort*)(ws + 2 * szW);
  ushort* h   = (ushort*)(ws + 3 * szW);

  float* out = (float*)d_out;

  k_pack_w13<<<dim3(I / 64, D / 64, 2 * E), 256, 0, stream>>>(w1, w3, w1p, w3p, D, I);
  k_pack_w2<<<dim3(D / 64, I / 64, E), 256, 0, stream>>>(w2, w2p, I, D);

  k_gemm1_8p<<<dim3((T / 256) * (I / 128)), 512, 0, stream>>>(x, w1p, w3p, g, h, T, D, I, E);
  k_gemm2_8p<<<dim3((T / 256) * (D / 256)), 512, 0, stream>>>(h, w2p, g, out, T, D, I, E);
}

// Round 7
// 1051.592 us; speedup vs baseline: 1.2684x; 1.2684x over previous
//
#include <hip/hip_runtime.h>
#include <hip/hip_bf16.h>

typedef __attribute__((ext_vector_type(8))) short bf16x8;
typedef __attribute__((ext_vector_type(4))) float f32x4;

#define SBAR() __builtin_amdgcn_sched_barrier(0)
#define WBAR() __builtin_amdgcn_s_barrier()

template<int N> __device__ __forceinline__ void vmcw() {
  if constexpr (N >= 12)     asm volatile("s_waitcnt vmcnt(12)" ::: "memory");
  else if constexpr (N == 8) asm volatile("s_waitcnt vmcnt(8)" ::: "memory");
  else if constexpr (N == 4) asm volatile("s_waitcnt vmcnt(4)" ::: "memory");
  else                       asm volatile("s_waitcnt vmcnt(0)" ::: "memory");
}

__device__ __forceinline__ ushort f2bf(float f) {
  union { float f; unsigned u; } v; v.f = f;
  unsigned r = v.u + 0x7fffu + ((v.u >> 16) & 1u);
  return (ushort)(r >> 16);
}

__device__ __forceinline__ void gld_lds16(const ushort* gsrc, ushort* lds) {
  __builtin_amdgcn_global_load_lds((const __attribute__((address_space(1))) void*)gsrc,
                                   (__attribute__((address_space(3))) void*)lds, 16, 0, 0);
}

__device__ __forceinline__ f32x4 MF(bf16x8 a, bf16x8 b, f32x4 c) {
  return __builtin_amdgcn_mfma_f32_16x16x32_bf16(a, b, c, 0, 0, 0);
}

__device__ __forceinline__ void xcd_map(int bid, int CT, int& r, int& c) {
  const int xcd = bid & 7, j = bid >> 3;
  r = xcd + 8 * (j / CT);
  c = j % CT;
}

__device__ __forceinline__ int expert_of(const int* g, int E, int m0) {
  int e = 0, base = 0;
  while (e < E - 1 && m0 >= base + g[e]) { base += g[e]; ++e; }
  return e;
}

// ================= pack x: [T][D] fp32 -> tiled-A bf16 (RB=256, BK=64, kc-major)
// tile(rt,kt) base = (rt*(D/64)+kt)*16384 ; within: kc*2048 + row*8 + j
__global__ __launch_bounds__(256) void k_pack_x(
    const float* __restrict__ x, ushort* __restrict__ xb, int D) {
  __shared__ ushort sm[256][66];
  const int kt = blockIdx.x;
  const int rt = blockIdx.y;
  const int t = threadIdx.x;
  const int c0 = kt * 64;
  const size_t r0 = (size_t)rt * 256;
#pragma unroll
  for (int p = 0; p < 16; ++p) {
    const int row = p * 16 + (t >> 4);
    const float4 v = *reinterpret_cast<const float4*>(x + (r0 + row) * D + c0 + (t & 15) * 4);
    ushort4 u; u.x = f2bf(v.x); u.y = f2bf(v.y); u.z = f2bf(v.z); u.w = f2bf(v.w);
    *reinterpret_cast<ushort4*>(&sm[row][(t & 15) * 4]) = u;
  }
  __syncthreads();
  ushort* outp = xb + ((size_t)rt * (D >> 6) + kt) * 16384;
#pragma unroll
  for (int p = 0; p < 8; ++p) {
    ushort u[8];
#pragma unroll
    for (int j = 0; j < 8; ++j) u[j] = sm[t][p * 8 + j];
    *reinterpret_cast<uint4*>(outp + p * 2048 + t * 8) = *reinterpret_cast<uint4*>(u);
  }
}

// ================= pack w1+w3: [E][D][I] fp32 -> tiled-B^T bf16 (RB=128) ======
// tile base = ((n>>7)*(D/64)+(k/64))*8192 ; within: kc*1024 + localrow*8 + (k&7)
__global__ __launch_bounds__(256) void k_pack_w13(
    const float* __restrict__ w1, const float* __restrict__ w3,
    ushort* __restrict__ w1p, ushort* __restrict__ w3p, int R, int C) {
  __shared__ ushort sm[64][66];
  const int bz = blockIdx.z;
  const int e = bz >> 1;
  const size_t mat = (size_t)R * C;
  const float* s = ((bz & 1) ? w3 : w1) + (size_t)e * mat;
  ushort* d = ((bz & 1) ? w3p : w1p) + (size_t)e * mat;
  const int c0 = blockIdx.x * 64;  // n
  const int r0 = blockIdx.y * 64;  // k
  const int t = threadIdx.x;
#pragma unroll
  for (int p = 0; p < 4; ++p) {
    const int r = p * 16 + (t >> 4);
    const float4 v = *reinterpret_cast<const float4*>(s + (size_t)(r0 + r) * C + c0 + (t & 15) * 4);
    ushort4 u; u.x = f2bf(v.x); u.y = f2bf(v.y); u.z = f2bf(v.z); u.w = f2bf(v.w);
    *reinterpret_cast<ushort4*>(&sm[r][(t & 15) * 4]) = u;
  }
  __syncthreads();
  const size_t tilebase = ((size_t)(c0 >> 7) * (R >> 6) + (r0 >> 6)) * 8192;
  const int nbase = c0 & 127;
#pragma unroll
  for (int p = 0; p < 2; ++p) {
    const int uu = p * 256 + t;
    const int kc = uu >> 6;
    const int rr = uu & 63;
    ushort u[8];
#pragma unroll
    for (int j = 0; j < 8; ++j) u[j] = sm[kc * 8 + j][rr];
    *reinterpret_cast<uint4*>(d + tilebase + (size_t)kc * 1024 + (size_t)(nbase + rr) * 8) =
        *reinterpret_cast<uint4*>(u);
  }
}

// ================= pack w2: [E][I][D] fp32 -> tiled-B^T bf16 (RB=256) ======
__global__ __launch_bounds__(256) void k_pack_w2(
    const float* __restrict__ w, ushort* __restrict__ wp, int R, int C) {
  __shared__ ushort sm[64][66];
  const int e = blockIdx.z;
  const size_t mat = (size_t)R * C;
  const float* s = w + (size_t)e * mat;
  ushort* d = wp + (size_t)e * mat;
  const int c0 = blockIdx.x * 64;  // n
  const int r0 = blockIdx.y * 64;  // k
  const int t = threadIdx.x;
#pragma unroll
  for (int p = 0; p < 4; ++p) {
    const int r = p * 16 + (t >> 4);
    const float4 v = *reinterpret_cast<const float4*>(s + (size_t)(r0 + r) * C + c0 + (t & 15) * 4);
    ushort4 u; u.x = f2bf(v.x); u.y = f2bf(v.y); u.z = f2bf(v.z); u.w = f2bf(v.w);
    *reinterpret_cast<ushort4*>(&sm[r][(t & 15) * 4]) = u;
  }
  __syncthreads();
  const size_t tilebase = ((size_t)(c0 >> 8) * (R >> 6) + (r0 >> 6)) * 16384;
  const int nbase = c0 & 255;
#pragma unroll
  for (int p = 0; p < 2; ++p) {
    const int uu = p * 256 + t;
    const int kc = uu >> 6;
    const int rr = uu & 63;
    ushort u[8];
#pragma unroll
    for (int j = 0; j < 8; ++j) u[j] = sm[kc * 8 + j][rr];
    *reinterpret_cast<uint4*>(d + tilebase + (size_t)kc * 2048 + (size_t)(nbase + rr) * 8) =
        *reinterpret_cast<uint4*>(u);
  }
}

// ================= GEMM1 tile body: 4 phases, prefetch distance 2 tiles =================
// buf: A[0,16384) ; B1[16384,24576) ; B3[24576,32768). kh0 = low half of each.
template<bool PF, int C1, int C2>
__device__ __forceinline__ void g1_tile(
    ushort* B, const ushort* nA, const ushort* nB1, const ushort* nB3,
    int sto, int aoff, int b1off, int b3off,
    f32x4 (&acc1)[8][2], f32x4 (&acc3)[8][2]) {
  bf16x8 af[4], b1f[2], b3f[2];
  // ---- P1: kh0, mi 0-3 ----
  SBAR();
#pragma unroll
  for (int mi = 0; mi < 4; ++mi) af[mi] = *(const bf16x8*)&B[aoff + mi * 128];
  b1f[0] = *(const bf16x8*)&B[b1off];       b1f[1] = *(const bf16x8*)&B[b1off + 128];
  b3f[0] = *(const bf16x8*)&B[b3off];       b3f[1] = *(const bf16x8*)&B[b3off + 128];
  SBAR(); WBAR(); SBAR();
  __builtin_amdgcn_s_setprio(1);
#pragma unroll
  for (int mi = 0; mi < 4; ++mi)
#pragma unroll
    for (int ni = 0; ni < 2; ++ni) {
      acc1[mi][ni] = MF(af[mi], b1f[ni], acc1[mi][ni]);
      acc3[mi][ni] = MF(af[mi], b3f[ni], acc3[mi][ni]);
    }
  __builtin_amdgcn_s_setprio(0);
  SBAR(); WBAR();
  // ---- P2: kh0, mi 4-7 ; refill kh0 slot with tile t+2 (WAR-safe after barrier) ----
  SBAR();
#pragma unroll
  for (int mi = 0; mi < 4; ++mi) af[mi] = *(const bf16x8*)&B[aoff + (mi + 4) * 128];
  SBAR(); WBAR(); SBAR();
  if (PF) {
    gld_lds16(nA + sto,         B + sto);
    gld_lds16(nA + 4096 + sto,  B + 4096 + sto);
    gld_lds16(nB1 + sto,        B + 16384 + sto);
    gld_lds16(nB3 + sto,        B + 24576 + sto);
  }
  __builtin_amdgcn_s_setprio(1);
#pragma unroll
  for (int mi = 0; mi < 4; ++mi)
#pragma unroll
    for (int ni = 0; ni < 2; ++ni) {
      acc1[mi + 4][ni] = MF(af[mi], b1f[ni], acc1[mi + 4][ni]);
      acc3[mi + 4][ni] = MF(af[mi], b3f[ni], acc3[mi + 4][ni]);
    }
  __builtin_amdgcn_s_setprio(0);
  SBAR();
  vmcw<C1>();   // gates kh1 of this tile (3 halves of slack remain)
  WBAR();
  // ---- P3: kh1, mi 0-3 ----
  SBAR();
#pragma unroll
  for (int mi = 0; mi < 4; ++mi) af[mi] = *(const bf16x8*)&B[aoff + 8192 + mi * 128];
  b1f[0] = *(const bf16x8*)&B[b1off + 4096]; b1f[1] = *(const bf16x8*)&B[b1off + 4096 + 128];
  b3f[0] = *(const bf16x8*)&B[b3off + 4096]; b3f[1] = *(const bf16x8*)&B[b3off + 4096 + 128];
  SBAR(); WBAR(); SBAR();
  __builtin_amdgcn_s_setprio(1);
#pragma unroll
  for (int mi = 0; mi < 4; ++mi)
#pragma unroll
    for (int ni = 0; ni < 2; ++ni) {
      acc1[mi][ni] = MF(af[mi], b1f[ni], acc1[mi][ni]);
      acc3[mi][ni] = MF(af[mi], b3f[ni], acc3[mi][ni]);
    }
  __builtin_amdgcn_s_setprio(0);
  SBAR(); WBAR();
  // ---- P4: kh1, mi 4-7 ; refill kh1 slot ----
  SBAR();
#pragma unroll
  for (int mi = 0; mi < 4; ++mi) af[mi] = *(const bf16x8*)&B[aoff + 8192 + (mi + 4) * 128];
  SBAR(); WBAR(); SBAR();
  if (PF) {
    gld_lds16(nA + 8192 + sto,   B + 8192 + sto);
    gld_lds16(nA + 12288 + sto,  B + 12288 + sto);
    gld_lds16(nB1 + 4096 + sto,  B + 20480 + sto);
    gld_lds16(nB3 + 4096 + sto,  B + 28672 + sto);
  }
  __builtin_amdgcn_s_setprio(1);
#pragma unroll
  for (int mi = 0; mi < 4; ++mi)
#pragma unroll
    for (int ni = 0; ni < 2; ++ni) {
      acc1[mi + 4][ni] = MF(af[mi], b1f[ni], acc1[mi + 4][ni]);
      acc3[mi + 4][ni] = MF(af[mi], b3f[ni], acc3[mi + 4][ni]);
    }
  __builtin_amdgcn_s_setprio(0);
  SBAR();
  vmcw<C2>();   // gates kh0 of tile t+1
  WBAR();
}

// ================= GEMM1: h = silu(x@w1)*(x@w3), 256x(128+128), BK=64 =================
__global__ __launch_bounds__(512, 2) void k_gemm1_8p(
    const ushort* __restrict__ xb, const ushort* __restrict__ w1p,
    const ushort* __restrict__ w3p, const int* __restrict__ g,
    ushort* __restrict__ h, int T, int D, int I, int E) {
  __shared__ ushort lds[2][32768];  // 128 KiB

  const int CT = I >> 7;
  int r, c; xcd_map(blockIdx.x, CT, r, c);
  const int m0 = r << 8, n0 = c << 7;
  const int e = expert_of(g, E, m0);

  const int tid = threadIdx.x;
  const int lane = tid & 63, wave = tid >> 6;
  const int wr = wave >> 2, wc = wave & 3;
  const int l15 = lane & 15, l16 = lane >> 4;

  const int KT = D >> 6;
  const ushort* pA  = xb  + (size_t)r * (D >> 6) * 16384;
  const ushort* pB1 = w1p + (size_t)e * I * D + (size_t)c * (D >> 6) * 8192;
  const ushort* pB3 = w3p + (size_t)e * I * D + (size_t)c * (D >> 6) * 8192;

  const int sto = tid * 8;
  const int aoff  = l16 * 2048 + (wr * 128 + l15) * 8;
  const int b1off = 16384 + l16 * 1024 + (wc * 32 + l15) * 8;
  const int b3off = b1off + 8192;

  const f32x4 zero = {0.f, 0.f, 0.f, 0.f};
  f32x4 acc1[8][2], acc3[8][2];
#pragma unroll
  for (int mi = 0; mi < 8; ++mi)
#pragma unroll
    for (int ni = 0; ni < 2; ++ni) { acc1[mi][ni] = zero; acc3[mi][ni] = zero; }

  // prologue: stage tiles 0 and 1, half-major issue order
  {
    ushort* L0 = lds[0]; ushort* L1 = lds[1];
    gld_lds16(pA + sto,          L0 + sto);
    gld_lds16(pA + 4096 + sto,   L0 + 4096 + sto);
    gld_lds16(pB1 + sto,         L0 + 16384 + sto);
    gld_lds16(pB3 + sto,         L0 + 24576 + sto);
    gld_lds16(pA + 8192 + sto,   L0 + 8192 + sto);
    gld_lds16(pA + 12288 + sto,  L0 + 12288 + sto);
    gld_lds16(pB1 + 4096 + sto,  L0 + 20480 + sto);
    gld_lds16(pB3 + 4096 + sto,  L0 + 28672 + sto);
    gld_lds16(pA + 16384 + sto,         L1 + sto);
    gld_lds16(pA + 16384 + 4096 + sto,  L1 + 4096 + sto);
    gld_lds16(pB1 + 8192 + sto,         L1 + 16384 + sto);
    gld_lds16(pB3 + 8192 + sto,         L1 + 24576 + sto);
    gld_lds16(pA + 16384 + 8192 + sto,  L1 + 8192 + sto);
    gld_lds16(pA + 16384 + 12288 + sto, L1 + 12288 + sto);
    gld_lds16(pB1 + 8192 + 4096 + sto,  L1 + 20480 + sto);
    gld_lds16(pB3 + 8192 + 4096 + sto,  L1 + 28672 + sto);
  }
  vmcw<12>(); WBAR(); SBAR();

  int t = 0;
  for (; t < KT - 2; ++t)
    g1_tile<true, 12, 12>(lds[t & 1], pA + (size_t)(t + 2) * 16384,
                          pB1 + (size_t)(t + 2) * 8192, pB3 + (size_t)(t + 2) * 8192,
                          sto, aoff, b1off, b3off, acc1, acc3);
  g1_tile<false, 8, 4>(lds[t & 1], pA, pB1, pB3, sto, aoff, b1off, b3off, acc1, acc3);
  ++t;
  g1_tile<false, 0, 0>(lds[t & 1], pA, pB1, pB3, sto, aoff, b1off, b3off, acc1, acc3);

  // epilogue: SwiGLU -> h in tiled-A layout (RB=256, K=I)
#pragma unroll
  for (int mi = 0; mi < 8; ++mi)
#pragma unroll
    for (int ni = 0; ni < 2; ++ni)
#pragma unroll
      for (int rr = 0; rr < 4; ++rr) {
        const float v1 = acc1[mi][ni][rr];
        const float v3 = acc3[mi][ni][rr];
        const float sv = v1 / (1.f + __expf(-v1));
        const int row = m0 + wr * 128 + mi * 16 + l16 * 4 + rr;
        const int col = n0 + wc * 32 + ni * 16 + l15;
        const size_t off = ((size_t)(row >> 8) * (I >> 6) + (col >> 6)) * 16384 +
                           ((col >> 3) & 7) * 2048 + (row & 255) * 8 + (col & 7);
        h[off] = f2bf(sv * v3);
      }
}

// ================= GEMM2 tile body (prefetch distance 2) =================
template<bool PF, int C1, int C2>
__device__ __forceinline__ void g2_tile(
    ushort* B, const ushort* nA, const ushort* nB,
    int sto, int aoff, int boff, f32x4 (&acc)[8][4]) {
  bf16x8 af[4], bf[4];
  // ---- P1 ----
  SBAR();
#pragma unroll
  for (int mi = 0; mi < 4; ++mi) af[mi] = *(const bf16x8*)&B[aoff + mi * 128];
#pragma unroll
  for (int ni = 0; ni < 4; ++ni) bf[ni] = *(const bf16x8*)&B[boff + ni * 128];
  SBAR(); WBAR(); SBAR();
  __builtin_amdgcn_s_setprio(1);
#pragma unroll
  for (int mi = 0; mi < 4; ++mi)
#pragma unroll
    for (int ni = 0; ni < 4; ++ni) acc[mi][ni] = MF(af[mi], bf[ni], acc[mi][ni]);
  __builtin_amdgcn_s_setprio(0);
  SBAR(); WBAR();
  // ---- P2 ----
  SBAR();
#pragma unroll
  for (int mi = 0; mi < 4; ++mi) af[mi] = *(const bf16x8*)&B[aoff + (mi + 4) * 128];
  SBAR(); WBAR(); SBAR();
  if (PF) {
    gld_lds16(nA + sto,         B + sto);
    gld_lds16(nA + 4096 + sto,  B + 4096 + sto);
    gld_lds16(nB + sto,         B + 16384 + sto);
    gld_lds16(nB + 4096 + sto,  B + 20480 + sto);
  }
  __builtin_amdgcn_s_setprio(1);
#pragma unroll
  for (int mi = 0; mi < 4; ++mi)
#pragma unroll
    for (int ni = 0; ni < 4; ++ni) acc[mi + 4][ni] = MF(af[mi], bf[ni], acc[mi + 4][ni]);
  __builtin_amdgcn_s_setprio(0);
  SBAR();
  vmcw<C1>();
  WBAR();
  // ---- P3 ----
  SBAR();
#pragma unroll
  for (int mi = 0; mi < 4; ++mi) af[mi] = *(const bf16x8*)&B[aoff + 8192 + mi * 128];
#pragma unroll
  for (int ni = 0; ni < 4; ++ni) bf[ni] = *(const bf16x8*)&B[boff + 8192 + ni * 128];
  SBAR(); WBAR(); SBAR();
  __builtin_amdgcn_s_setprio(1);
#pragma unroll
  for (int mi = 0; mi < 4; ++mi)
#pragma unroll
    for (int ni = 0; ni < 4; ++ni) acc[mi][ni] = MF(af[mi], bf[ni], acc[mi][ni]);
  __builtin_amdgcn_s_setprio(0);
  SBAR(); WBAR();
  // ---- P4 ----
  SBAR();
#pragma unroll
  for (int mi = 0; mi < 4; ++mi) af[mi] = *(const bf16x8*)&B[aoff + 8192 + (mi + 4) * 128];
  SBAR(); WBAR(); SBAR();
  if (PF) {
    gld_lds16(nA + 8192 + sto,   B + 8192 + sto);
    gld_lds16(nA + 12288 + sto,  B + 12288 + sto);
    gld_lds16(nB + 8192 + sto,   B + 24576 + sto);
    gld_lds16(nB + 12288 + sto,  B + 28672 + sto);
  }
  __builtin_amdgcn_s_setprio(1);
#pragma unroll
  for (int mi = 0; mi < 4; ++mi)
#pragma unroll
    for (int ni = 0; ni < 4; ++ni) acc[mi + 4][ni] = MF(af[mi], bf[ni], acc[mi + 4][ni]);
  __builtin_amdgcn_s_setprio(0);
  SBAR();
  vmcw<C2>();
  WBAR();
}

// ================= GEMM2: out = h @ w2, 256x256, BK=64, fp32 out =================
__global__ __launch_bounds__(512, 2) void k_gemm2_8p(
    const ushort* __restrict__ h, const ushort* __restrict__ w2p,
    const int* __restrict__ g, float* __restrict__ out,
    int T, int D, int I, int E) {
  __shared__ ushort lds[2][32768];

  const int CT = D >> 8;
  int r, cb; xcd_map(blockIdx.x, CT, r, cb);
  const int m0 = r << 8, n0 = cb << 8;
  const int e = expert_of(g, E, m0);

  const int tid = threadIdx.x;
  const int lane = tid & 63, wave = tid >> 6;
  const int wr = wave >> 2, wc = wave & 3;
  const int l15 = lane & 15, l16 = lane >> 4;

  const int KT = I >> 6;
  const ushort* pA = h   + (size_t)r * (I >> 6) * 16384;
  const ushort* pB = w2p + (size_t)e * D * I + (size_t)cb * (I >> 6) * 16384;

  const int sto = tid * 8;
  const int aoff = l16 * 2048 + (wr * 128 + l15) * 8;
  const int boff = 16384 + l16 * 2048 + (wc * 64 + l15) * 8;

  const f32x4 zero = {0.f, 0.f, 0.f, 0.f};
  f32x4 acc[8][4];
#pragma unroll
  for (int mi = 0; mi < 8; ++mi)
#pragma unroll
    for (int ni = 0; ni < 4; ++ni) acc[mi][ni] = zero;

  {
    ushort* L0 = lds[0]; ushort* L1 = lds[1];
    gld_lds16(pA + sto,          L0 + sto);
    gld_lds16(pA + 4096 + sto,   L0 + 4096 + sto);
    gld_lds16(pB + sto,          L0 + 16384 + sto);
    gld_lds16(pB + 4096 + sto,   L0 + 20480 + sto);
    gld_lds16(pA + 8192 + sto,   L0 + 8192 + sto);
    gld_lds16(pA + 12288 + sto,  L0 + 12288 + sto);
    gld_lds16(pB + 8192 + sto,   L0 + 24576 + sto);
    gld_lds16(pB + 12288 + sto,  L0 + 28672 + sto);
    gld_lds16(pA + 16384 + sto,          L1 + sto);
    gld_lds16(pA + 16384 + 4096 + sto,   L1 + 4096 + sto);
    gld_lds16(pB + 16384 + sto,          L1 + 16384 + sto);
    gld_lds16(pB + 16384 + 4096 + sto,   L1 + 20480 + sto);
    gld_lds16(pA + 16384 + 8192 + sto,   L1 + 8192 + sto);
    gld_lds16(pA + 16384 + 12288 + sto,  L1 + 12288 + sto);
    gld_lds16(pB + 16384 + 8192 + sto,   L1 + 24576 + sto);
    gld_lds16(pB + 16384 + 12288 + sto,  L1 + 28672 + sto);
  }
  vmcw<12>(); WBAR(); SBAR();

  int t = 0;
  for (; t < KT - 2; ++t)
    g2_tile<true, 12, 12>(lds[t & 1], pA + (size_t)(t + 2) * 16384,
                          pB + (size_t)(t + 2) * 16384, sto, aoff, boff, acc);
  g2_tile<false, 8, 4>(lds[t & 1], pA, pB, sto, aoff, boff, acc);
  ++t;
  g2_tile<false, 0, 0>(lds[t & 1], pA, pB, sto, aoff, boff, acc);

#pragma unroll
  for (int mi = 0; mi < 8; ++mi)
#pragma unroll
    for (int ni = 0; ni < 4; ++ni)
#pragma unroll
      for (int rr = 0; rr < 4; ++rr) {
        const int row = m0 + wr * 128 + mi * 16 + l16 * 4 + rr;
        const int col = n0 + wc * 64 + ni * 16 + l15;
        out[(size_t)row * D + col] = acc[mi][ni][rr];
      }
}

// ================= launch =================
extern "C" void kernel_launch(void* const* d_in, const int* in_sizes, int n_in,
                              void* d_out, int out_size, void* d_ws, size_t ws_size,
                              hipStream_t stream) {
  const float* x  = (const float*)d_in[0];
  const float* w1 = (const float*)d_in[1];
  const float* w2 = (const float*)d_in[2];
  const float* w3 = (const float*)d_in[3];
  const int*   g  = (const int*)d_in[4];

  const int E = in_sizes[4];
  const int D = 4096;
  const int I = 1024;
  const int T = in_sizes[0] / D;

  const size_t szW = (size_t)E * D * I * sizeof(ushort);  // 64 MB
  const size_t szH = (size_t)T * I * sizeof(ushort);      // 64 MB
  const size_t szX = (size_t)T * D * sizeof(ushort);      // 256 MB
  const size_t need = 2 * szW + szH + szX;                // 448 MB (proven available)
  if (ws_size < need) return;

  char* ws = (char*)d_ws;
  ushort* w1p = (ushort*)ws;              // slot 0 (reused by w2p after gemm1)
  ushort* w3p = (ushort*)(ws + szW);      // slot 1
  ushort* h   = (ushort*)(ws + 2 * szW);  // slot 2
  ushort* xb  = (ushort*)(ws + 2 * szW + szH);
  ushort* w2p = w1p;

  float* out = (float*)d_out;

  k_pack_w13<<<dim3(I / 64, D / 64, 2 * E), 256, 0, stream>>>(w1, w3, w1p, w3p, D, I);
  k_pack_x<<<dim3(D / 64, T / 256), 256, 0, stream>>>(x, xb, D);

  k_gemm1_8p<<<dim3((T / 256) * (I / 128)), 512, 0, stream>>>(xb, w1p, w3p, g, h, T, D, I, E);

  k_pack_w2<<<dim3(D / 64, I / 64, E), 256, 0, stream>>>(w2, w2p, I, D);

  k_gemm2_8p<<<dim3((T / 256) * (D / 256)), 512, 0, stream>>>(h, w2p, g, out, T, D, I, E);
}